// Round 11
// baseline (66.683 us; speedup 1.0000x reference)
//
#include <hip/hip_runtime.h>
#include <stdint.h>

// NFP pooling: out[b,o,i,j] = -sum_c |x[b,c,i+1,j+1] - x[b,c,i+di,j+dj]|
// x: (8,128,224,224) f32 -> out: (8,8,222,222) f32.
//
// R11: R10 with doubled tile height. Block = 8 output rows x 222 cols,
// 512 threads; 32 rounds of KC=4 channels staging 10-row strips (35.8 KB)
// via global_load_lds w16, double-buffered, one barrier per round.
// Staged traffic 308 -> 256 MB (1.25x input). XCD pinning kept:
// 224 blocks = 8 batches x 28 tiles, bid&7 = batch.

constexpr int C = 128;
constexpr int H = 224;
constexpr int W = 224;
constexpr int HO = 222;
constexpr int WO = 222;
constexpr int PLANE = H * W;              // 50176
constexpr int OPLANE = HO * WO;           // 49284
constexpr int KC = 4;                     // channels per round
constexpr int ROUNDS = C / KC;            // 32
constexpr int TROWS = 8;                  // output rows per tile
constexpr int SROWS = 10;                 // staged input rows
constexpr int NT = 28;                    // row tiles per batch (28*8=224>=222)
constexpr int NBLK = 8 * NT;              // 224
constexpr int NTHR = 512;
constexpr int SLOTS = KC * SROWS * (W / 4);   // 2240 16-B slots per buffer

__device__ __forceinline__ void gload16(const float* g, float* l) {
    __builtin_amdgcn_global_load_lds(
        (const __attribute__((address_space(1))) void*)g,
        (__attribute__((address_space(3))) void*)l, 16, 0, 0);
}

__global__ __launch_bounds__(NTHR, 1)
void nfp_sad_kernel(const float* __restrict__ x, float* __restrict__ out) {
    __shared__ float lds[2][SLOTS * 4];   // 2 x 35,840 B = 71,680 B

    int bid = blockIdx.x;
    int b = bid & 7;                      // batch == XCD (224 = 8*28)
    int t = bid >> 3;                     // row tile 0..27
    int i0 = t * TROWS;                   // first output row; staged rows i0..i0+9
    int tid = threadIdx.x;

    // --- staging slots: v = j*512 + tid, v < 2240 ---
    // v -> c = v/560, r = (v%560)/56, k = v%56 ; row clamped to 223
    const float* xb = x + (size_t)b * C * PLANE;
    int goff[5];
#pragma unroll
    for (int j = 0; j < 5; ++j) {
        int v = j * NTHR + tid;
        int vv = v < SLOTS ? v : SLOTS - 1;
        int c = vv / 560, rem = vv % 560;
        int r = rem / 56, k = rem % 56;
        int row = i0 + r; if (row > H - 1) row = H - 1;
        goff[j] = c * PLANE + row * W + k * 4;
    }

    // --- compute role: tid < 444 active; rp = tid/111 (0..3), cp = tid%111 ---
    bool act = tid < 444;
    int rp = act ? (tid / 111) : 0;       // rowpair within tile
    int cp = act ? (tid % 111) : 0;       // colpair: output cols 2cp, 2cp+1

    float acc0[8][2], acc1[8][2];
#pragma unroll
    for (int o = 0; o < 8; ++o) {
        acc0[o][0] = acc0[o][1] = 0.0f;
        acc1[o][0] = acc1[o][1] = 0.0f;
    }

    // stage round 0
    {
        float* dst = &lds[0][0];
#pragma unroll
        for (int j = 0; j < 4; ++j)
            gload16(xb + goff[j], dst + (j * NTHR + tid) * 4);
        if (tid < SLOTS - 4 * NTHR)       // 192 tail slots
            gload16(xb + goff[4], dst + (4 * NTHR + tid) * 4);
    }

    int choff = 0;                        // channel offset (floats)
    for (int rd = 0; rd < ROUNDS; ++rd) {
        __syncthreads();                  // stage(rd) complete (drains vmcnt)

        if (rd + 1 < ROUNDS) {            // issue DMA for next round
            int noff = choff + KC * PLANE;
            float* dst = &lds[(rd + 1) & 1][0];
#pragma unroll
            for (int j = 0; j < 4; ++j)
                gload16(xb + noff + goff[j], dst + (j * NTHR + tid) * 4);
            if (tid < SLOTS - 4 * NTHR)
                gload16(xb + noff + goff[4], dst + (4 * NTHR + tid) * 4);
        }

        if (act) {
            const float* Bf = &lds[rd & 1][0];
#pragma unroll
            for (int c = 0; c < KC; ++c) {
                // staged rows 2rp..2rp+3, cols 2cp..2cp+3
                const float* pc = Bf + (c * SROWS + 2 * rp) * W + 2 * cp;
                float v0[4], v1[4], v2[4], v3[4];
                *(float2*)&v0[0] = *(const float2*)(pc);
                *(float2*)&v0[2] = *(const float2*)(pc + 2);
                *(float2*)&v1[0] = *(const float2*)(pc + W);
                *(float2*)&v1[2] = *(const float2*)(pc + W + 2);
                *(float2*)&v2[0] = *(const float2*)(pc + 2 * W);
                *(float2*)&v2[2] = *(const float2*)(pc + 2 * W + 2);
                *(float2*)&v3[0] = *(const float2*)(pc + 3 * W);
                *(float2*)&v3[2] = *(const float2*)(pc + 3 * W + 2);

                float hh1[3], hh2[3], DR[3], DL[3], Vv[2];
#pragma unroll
                for (int k = 0; k < 3; ++k) {
                    hh1[k] = __builtin_fabsf(v1[k + 1] - v1[k]);
                    hh2[k] = __builtin_fabsf(v2[k + 1] - v2[k]);
                    DR[k]  = __builtin_fabsf(v1[k + 1] - v2[k]);
                    DL[k]  = __builtin_fabsf(v1[k] - v2[k + 1]);
                }
                Vv[0] = __builtin_fabsf(v1[1] - v2[1]);
                Vv[1] = __builtin_fabsf(v1[2] - v2[2]);

                // offset order: (0,0),(0,1),(0,2),(1,0),(1,2),(2,0),(2,1),(2,2)
#pragma unroll
                for (int q = 0; q < 2; ++q) {
                    float c1 = v1[q + 1], c2 = v2[q + 1];
                    acc0[0][q] += __builtin_fabsf(c1 - v0[q]);
                    acc0[1][q] += __builtin_fabsf(c1 - v0[q + 1]);
                    acc0[2][q] += __builtin_fabsf(c1 - v0[q + 2]);
                    acc0[3][q] += hh1[q];
                    acc0[4][q] += hh1[q + 1];
                    acc0[5][q] += DR[q];
                    acc0[6][q] += Vv[q];
                    acc0[7][q] += DL[q + 1];
                    acc1[0][q] += DL[q];
                    acc1[1][q] += Vv[q];
                    acc1[2][q] += DR[q + 1];
                    acc1[3][q] += hh2[q];
                    acc1[4][q] += hh2[q + 1];
                    acc1[5][q] += __builtin_fabsf(c2 - v3[q]);
                    acc1[6][q] += __builtin_fabsf(c2 - v3[q + 1]);
                    acc1[7][q] += __builtin_fabsf(c2 - v3[q + 2]);
                }
            }
        }
        choff += KC * PLANE;
    }

    if (act) {
        int r0 = i0 + 2 * rp;             // first of this thread's 2 output rows
        float* ob = out + (size_t)b * 8 * OPLANE + 2 * cp;
#pragma unroll
        for (int o = 0; o < 8; ++o) {
            float* op = ob + (size_t)o * OPLANE;
            if (r0 < HO)
                *(float2*)(op + (size_t)r0 * WO) = make_float2(-acc0[o][0], -acc0[o][1]);
            if (r0 + 1 < HO)
                *(float2*)(op + (size_t)(r0 + 1) * WO) = make_float2(-acc1[o][0], -acc1[o][1]);
        }
    }
}

extern "C" void kernel_launch(void* const* d_in, const int* in_sizes, int n_in,
                              void* d_out, int out_size, void* d_ws, size_t ws_size,
                              hipStream_t stream) {
    const float* x = (const float*)d_in[0];
    float* out = (float*)d_out;
    nfp_sad_kernel<<<NBLK, NTHR, 0, stream>>>(x, out);
}